// Round 1
// baseline (197.052 us; speedup 1.0000x reference)
//
#include <hip/hip_runtime.h>

#define BB 4
#define NN 2048
#define INF 256
#define HH 8
#define DD 32
#define LOG2E 1.4426950408889634f

typedef __attribute__((ext_vector_type(8))) short short8;
typedef __attribute__((ext_vector_type(4))) float f32x4;

__device__ __forceinline__ unsigned short bf16_rne(float v) {
    unsigned b = __float_as_uint(v);
    return (unsigned short)((b + 0x7fffu + ((b >> 16) & 1u)) >> 16);
}
__device__ __forceinline__ unsigned short bf16_rhu(float v) {
    return (unsigned short)((__float_as_uint(v) + 0x8000u) >> 16);
}

// Fused prep kernel, role = blockIdx.x & 3:
//  role 0 (512 blocks): whk  — Wh GEMM -> whT2 bf16; W->LDS bf16 transpose inline
//  role 1 (512 blocks): ek   — exact fp32 e-dots -> esrc (log2-scaled), ejP packed;
//                              we (W·a) computed inline (a is wave-uniform -> s_loads)
//  role 2/3 (1024 blocks): adjbits — adj int32 -> bitmask, LSB = lowest j
__global__ __launch_bounds__(256) void prep_kernel(
    const float* __restrict__ x, const int* __restrict__ adj,
    const float* __restrict__ W, const float* __restrict__ a,
    unsigned short* __restrict__ whT2, float* __restrict__ esrc,
    unsigned* __restrict__ ejP, unsigned* __restrict__ bitsG)
{
    __shared__ __align__(16) unsigned short smem[64 * 264 * 2];
    const int bid = blockIdx.x, t = threadIdx.x;
    const int role = bid & 3;

    if (role >= 2) {                       // ---- adjbits ----
        const int id = (bid >> 2) * 2 + (role - 2);     // 0..1023
        const int w64 = t & 63;
        #pragma unroll
        for (int rr = 0; rr < 2; ++rr) {
            int row = id * 8 + (t >> 6) + rr * 4;       // global (b*N + i) row
            const int* ap = adj + (size_t)row * NN + w64 * 32;
            unsigned word = 0;
            #pragma unroll
            for (int u = 0; u < 8; ++u) {
                int4 g = *(const int4*)&ap[u * 4];
                unsigned nib = (g.x != 0 ? 1u : 0u) | (g.y != 0 ? 2u : 0u)
                             | (g.z != 0 ? 4u : 0u) | (g.w != 0 ? 8u : 0u);
                word |= nib << (u * 4);
            }
            bitsG[(size_t)row * 64 + w64] = word;
        }
        return;
    }

    if (role == 0) {                       // ---- whk ----
        unsigned short* xb = smem;                       // [64][264]
        unsigned short* wb = smem + 64 * 264;            // [64][264]
        const int id = bid >> 2;
        const int hp = id & 3, tl = (id >> 2) & 31, b = id >> 7;
        const int n0 = tl * 64;

        #pragma unroll
        for (int p = 0; p < 16; ++p) {                   // x tile -> bf16 LDS
            int flat = p * 1024 + t * 4;
            int row = flat >> 8, col = flat & 255;
            f32x4 g = *(const f32x4*)&x[((size_t)(b * NN + n0 + row)) * INF + col];
            unsigned a0 = __float_as_uint(g[0]) + 0x8000u;
            unsigned a1 = __float_as_uint(g[1]) + 0x8000u;
            unsigned a2 = __float_as_uint(g[2]) + 0x8000u;
            unsigned a3 = __float_as_uint(g[3]) + 0x8000u;
            uint2 pk;
            pk.x = __builtin_amdgcn_perm(a1, a0, 0x07060302u);
            pk.y = __builtin_amdgcn_perm(a3, a2, 0x07060302u);
            *(uint2*)&xb[row * 264 + col] = pk;
        }
        #pragma unroll
        for (int p = 0; p < 16; ++p) {                   // W slice (fp32) -> wb^T bf16
            int flat = p * 1024 + t * 4;                 // 16384 floats = 2 heads
            int h2 = flat >> 13, rem = flat & 8191;
            int f = rem >> 5, d0 = rem & 31;
            f32x4 g = *(const f32x4*)&W[(((size_t)(hp * 2 + h2)) * INF + f) * DD + d0];
            #pragma unroll
            for (int i = 0; i < 4; ++i)
                wb[(h2 * 32 + d0 + i) * 264 + f] = bf16_rhu(g[i]);
        }
        __syncthreads();

        const int w = t >> 6, l = t & 63;
        const int ml = l & 15, q = l >> 4;
        f32x4 acc[4] = {};
        const unsigned short* apx = &xb[(w * 16 + ml) * 264 + q * 8];
        #pragma unroll
        for (int k0 = 0; k0 < INF; k0 += 32) {
            short8 A = *(const short8*)&apx[k0];
            #pragma unroll
            for (int c16 = 0; c16 < 4; ++c16) {
                short8 Bf = *(const short8*)&wb[(c16 * 16 + ml) * 264 + q * 8 + k0];
                acc[c16] = __builtin_amdgcn_mfma_f32_16x16x32_bf16(A, Bf, acc[c16], 0, 0, 0);
            }
        }
        __syncthreads();
        unsigned short* ldsC = xb;                       // [64 col][72 row]
        #pragma unroll
        for (int c16 = 0; c16 < 4; ++c16)
            #pragma unroll
            for (int r = 0; r < 4; ++r) {
                int col = c16 * 16 + ml;
                int rt  = w * 16 + q * 4 + r;
                ldsC[col * 72 + rt] = bf16_rhu(acc[c16][r]);
            }
        __syncthreads();
        #pragma unroll
        for (int p = 0; p < 2; ++p) {
            int g = p * 256 + t;
            int d = g & 31, jo = (g >> 5) & 7, h2 = g >> 8;
            short8 vv = *(const short8*)&ldsC[(h2 * 32 + d) * 72 + jo * 8];
            int bh = b * 8 + hp * 2 + h2;
            *(short8*)&whT2[(((size_t)bh * 256 + tl * 8 + jo) * 32 + d) * 8] = vv;
        }
        return;
    }

    // ---- role 1: ek ----
    float* xs    = (float*)smem;                         // [16][260]
    float* weld2 = (float*)smem + 16 * 260;              // [c=f>>4][k*16+fi]
    const int id = bid >> 2;
    const int tile = id & 127, b = id >> 7;
    const int n0 = tile * 16;

    #pragma unroll
    for (int p = 0; p < 4; ++p) {
        int flat = p * 1024 + t * 4;
        int row = flat >> 8, col = flat & 255;
        f32x4 g = *(const f32x4*)&x[((size_t)(b * NN + n0 + row)) * INF + col];
        *(f32x4*)&xs[row * 260 + col] = g;
    }
    {   // inline we: thread t owns f-column t; a[] is uniform -> scalar loads
        const int f = t;
        #pragma unroll
        for (int h = 0; h < 8; ++h) {
            const float* wr = W + ((size_t)(h * INF + f)) * DD;
            float s0 = 0.f, s1 = 0.f;
            #pragma unroll
            for (int d = 0; d < DD; ++d) {
                float wv = wr[d];
                s0 += wv * a[h * 2 * DD + d];
                s1 += wv * a[h * 2 * DD + DD + d];
            }
            weld2[(f >> 4) * 260 + h * 16 + (f & 15)]       = s0 * LOG2E;
            weld2[(f >> 4) * 260 + (h + 8) * 16 + (f & 15)] = s1 * LOG2E;
        }
    }
    __syncthreads();

    const int row = t >> 4, cc = t & 15;
    f32x4 xv[4];
    #pragma unroll
    for (int i = 0; i < 4; ++i)
        xv[i] = *(const f32x4*)&xs[row * 260 + cc * 16 + i * 4];

    float keep = 0.f;
    #pragma unroll
    for (int k = 0; k < 16; ++k) {
        float s = 0.f;
        #pragma unroll
        for (int i = 0; i < 4; ++i) {
            f32x4 w4 = *(const f32x4*)&weld2[cc * 260 + k * 16 + i * 4];
            s += xv[i][0]*w4[0] + xv[i][1]*w4[1] + xv[i][2]*w4[2] + xv[i][3]*w4[3];
        }
        s += __shfl_xor(s, 1, 64);
        s += __shfl_xor(s, 2, 64);
        s += __shfl_xor(s, 4, 64);
        s += __shfl_xor(s, 8, 64);
        keep = (cc == k) ? s : keep;
    }
    const int n = n0 + row;
    if (cc < 8) {
        esrc[(b * 8 + cc) * NN + n] = keep;
    } else {
        float Ej  = __builtin_amdgcn_exp2f(keep);
        float Ej5 = __builtin_amdgcn_exp2f(0.2f * keep);
        ejP[(b * 8 + (cc - 8)) * NN + n] =
            ((unsigned)bf16_rne(Ej) << 16) | (unsigned)bf16_rne(Ej5);
    }
}

// attn: barrier-free, zero LDS. 1024 blocks x 256 thr; block = (b, 16-row tile,
// head group of 4); wave = one head, 16 i-rows x full j. p' = max(Ej, Fj*Gi) with
// Gi = 2^(-0.8*ei) — per-row scale cancels in the softmax ratio, Ei mult removed.
// adj bits pre-compressed in prep -> direct uint4 loads, no ballot/LDS/barriers.
__global__ __launch_bounds__(256, 4) void attn_kernel(
    const unsigned short* __restrict__ whT2, const float* __restrict__ esrc,
    const unsigned* __restrict__ ejP, const unsigned* __restrict__ bitsG,
    float* __restrict__ out)
{
    const int t = threadIdx.x, v = t >> 6, l = t & 63;
    const int ml = l & 15, q = l >> 4;
    const int bid = blockIdx.x;
    const int hg = bid & 1;
    const int it = (bid >> 1) & 127;
    const int b = bid >> 8;
    const int h = hg * 4 + v;
    const int i0 = it * 16;
    const int bh = b * HH + h;

    const float ei = esrc[bh * NN + i0 + ml];
    const float Gi = __builtin_amdgcn_exp2f(-0.8f * ei);

    const unsigned* epP = ejP + bh * NN;
    const unsigned short* whb = whT2 + (size_t)bh * (256 * DD * 8);
    const unsigned* mbase = bitsG + ((size_t)(b * NN + i0 + ml)) * 64;

    const short8 ones = {0x3F80, 0x3F80, 0x3F80, 0x3F80,
                         0x3F80, 0x3F80, 0x3F80, 0x3F80};
    f32x4 accP = {}, accQ = {}, accD = {};

    for (int c = 0; c < 16; ++c) {
        uint4 mrow = *(const uint4*)&mbase[c * 4];
        const unsigned* epc = epP + c * 128;
        const unsigned mw[4] = {mrow.x, mrow.y, mrow.z, mrow.w};
        #pragma unroll
        for (int k = 0; k < 4; ++k) {
            const int jb = k * 32 + q * 8;
            uint4 epA = *(const uint4*)&epc[jb];
            uint4 epB = *(const uint4*)&epc[jb + 4];
            const unsigned short* wp = whb + (size_t)((c * 16 + k * 4 + q) * 256);
            short8 B0 = *(const short8*)&wp[ml * 8];
            short8 B1 = *(const short8*)&wp[(16 + ml) * 8];
            unsigned st = mw[k] >> (q * 8);
            union { unsigned u[4]; short8 s; } f0;
            const unsigned* ea = &epA.x;
            const unsigned* eb = &epB.x;
            #pragma unroll
            for (int pp = 0; pp < 4; ++pp) {
                unsigned pkA = (pp < 2) ? ea[2 * pp]     : eb[2 * pp - 4];
                unsigned pkB = (pp < 2) ? ea[2 * pp + 1] : eb[2 * pp - 3];
                float EjA = __uint_as_float(pkA & 0xffff0000u);
                float FjA = __uint_as_float(pkA << 16);
                float EjB = __uint_as_float(pkB & 0xffff0000u);
                float FjB = __uint_as_float(pkB << 16);
                unsigned mA = (unsigned)__builtin_amdgcn_sbfe(st, 2 * pp, 1);
                unsigned mB = (unsigned)__builtin_amdgcn_sbfe(st, 2 * pp + 1, 1);
                float pA = fmaxf(EjA, FjA * Gi);
                float pB = fmaxf(EjB, FjB * Gi);
                f0.u[pp] = __builtin_amdgcn_perm(__float_as_uint(pB) & mB,
                                                 __float_as_uint(pA) & mA,
                                                 0x07060302u);
            }
            accP = __builtin_amdgcn_mfma_f32_16x16x32_bf16(f0.s, B0, accP, 0, 0, 0);
            accQ = __builtin_amdgcn_mfma_f32_16x16x32_bf16(f0.s, B1, accQ, 0, 0, 0);
            accD = __builtin_amdgcn_mfma_f32_16x16x32_bf16(f0.s, ones, accD, 0, 0, 0);
        }
    }

    #pragma unroll
    for (int r = 0; r < 4; ++r) {
        int ir = i0 + q * 4 + r;
        float inv = 1.0f / accD[r];
        size_t ba = ((size_t)(b * NN + ir)) * (HH * DD) + h * DD;
        out[ba + ml]      = accP[r] * inv;
        out[ba + 16 + ml] = accQ[r] * inv;
    }
}

extern "C" void kernel_launch(void* const* d_in, const int* in_sizes, int n_in,
                              void* d_out, int out_size, void* d_ws, size_t ws_size,
                              hipStream_t stream) {
    (void)in_sizes; (void)n_in; (void)out_size; (void)ws_size;
    const float* x   = (const float*)d_in[0];
    const int*   adj = (const int*)d_in[1];
    const float* W   = (const float*)d_in[2];
    const float* a   = (const float*)d_in[3];
    float* out = (float*)d_out;

    char* ws = (char*)d_ws;
    unsigned short* whT2 = (unsigned short*)ws;                          // 4 MB
    float*    esrc  = (float*)(ws + (4u << 20));                         // 256 KB
    unsigned* ejP   = (unsigned*)(ws + (4u << 20) + (256u << 10));       // 256 KB
    unsigned* bitsG = (unsigned*)(ws + (4u << 20) + (512u << 10));       // 2 MB

    prep_kernel<<<dim3(2048), dim3(256), 0, stream>>>(x, adj, W, a,
                                                      whT2, esrc, ejP, bitsG);
    attn_kernel<<<dim3(1024), dim3(256), 0, stream>>>(whT2, esrc, ejP, bitsG, out);
}